// Round 4
// baseline (254.593 us; speedup 1.0000x reference)
//
#include <hip/hip_runtime.h>

#define DEPTH 128
#define GPB 16   // graphs per block in the MLP kernel

// clang-native float4 so __builtin_nontemporal_load accepts the pointer
typedef float f4 __attribute__((ext_vector_type(4)));

// Kernel 1: one block per graph. Threads 0/1 binary-search the block's row
// range (batch is sorted), then the block streams its rows with pipelined
// nontemporal float4 loads, reduces sum/max in LDS, writes [max|mean|sum]
// (384 floats) to ws.
__global__ __launch_bounds__(256) void pool_kernel(
    const f4* __restrict__ x4, const int* __restrict__ batch,
    float* __restrict__ pooled, int N, int G)
{
    const int g   = blockIdx.x;
    const int tid = threadIdx.x;
    const int rg  = tid >> 5;   // row group 0..7
    const int d4  = tid & 31;   // float4 column 0..31

    __shared__ int sbounds[2];
    if (tid < 2) {
        const int target = g + tid;
        int lo = 0, hi = N;
        while (lo < hi) {
            int mid = (lo + hi) >> 1;
            if (batch[mid] < target) lo = mid + 1; else hi = mid;
        }
        sbounds[tid] = lo;
    }
    __syncthreads();
    const int s0 = sbounds[0];
    const int s1 = sbounds[1];

    f4 sum0 = (f4)(0.f);
    f4 sum1 = sum0, sum2 = sum0, sum3 = sum0;
    f4 mx0 = (f4)(-INFINITY);
    f4 mx1 = mx0, mx2 = mx0, mx3 = mx0;

#define LOADX(rr) __builtin_nontemporal_load(&x4[(size_t)(rr) * 32 + d4])
#define ACC(v, s, m) do { \
        (s) += (v); \
        (m).x = fmaxf((m).x, (v).x); (m).y = fmaxf((m).y, (v).y); \
        (m).z = fmaxf((m).z, (v).z); (m).w = fmaxf((m).w, (v).w); } while (0)

    int r = s0 + rg;
    if (r + 24 < s1) {
        // prologue: first 4 loads in flight
        f4 v0 = LOADX(r), v1 = LOADX(r + 8), v2 = LOADX(r + 16), v3 = LOADX(r + 24);
        int rn = r + 32;
        for (; rn + 24 < s1; rn += 32) {
            // issue next 4 before consuming current 4 -> 8 loads in flight
            f4 n0 = LOADX(rn),      n1 = LOADX(rn + 8);
            f4 n2 = LOADX(rn + 16), n3 = LOADX(rn + 24);
            ACC(v0, sum0, mx0); ACC(v1, sum1, mx1);
            ACC(v2, sum2, mx2); ACC(v3, sum3, mx3);
            v0 = n0; v1 = n1; v2 = n2; v3 = n3;
        }
        ACC(v0, sum0, mx0); ACC(v1, sum1, mx1);
        ACC(v2, sum2, mx2); ACC(v3, sum3, mx3);
        r = rn;
    }
    for (; r < s1; r += 8) {
        f4 v = LOADX(r);
        ACC(v, sum0, mx0);
    }
#undef ACC
#undef LOADX

    // fold 4 accumulator sets
    f4 sum = sum0 + sum1 + sum2 + sum3;
    f4 mx;
    mx.x = fmaxf(fmaxf(mx0.x, mx1.x), fmaxf(mx2.x, mx3.x));
    mx.y = fmaxf(fmaxf(mx0.y, mx1.y), fmaxf(mx2.y, mx3.y));
    mx.z = fmaxf(fmaxf(mx0.z, mx1.z), fmaxf(mx2.z, mx3.z));
    mx.w = fmaxf(fmaxf(mx0.w, mx1.w), fmaxf(mx2.w, mx3.w));

    __shared__ f4 redS[8][32];
    __shared__ f4 redM[8][32];
    redS[rg][d4] = sum;
    redM[rg][d4] = mx;
    __syncthreads();

    if (tid < 32) {
        f4 s = redS[0][d4];
        f4 m = redM[0][d4];
        #pragma unroll
        for (int i = 1; i < 8; ++i) {
            s += redS[i][d4];
            f4 tm = redM[i][d4];
            m.x = fmaxf(m.x, tm.x); m.y = fmaxf(m.y, tm.y);
            m.z = fmaxf(m.z, tm.z); m.w = fmaxf(m.w, tm.w);
        }
        const int cnt = s1 - s0;
        const float inv = 1.0f / (float)(cnt > 1 ? cnt : 1);
        if (cnt == 0) m = (f4)(0.f);
        f4 mean4 = s * inv;
        f4* prow = reinterpret_cast<f4*>(pooled + (size_t)g * 3 * DEPTH);
        prow[d4]      = m;      // max   [0:128)
        prow[32 + d4] = mean4;  // mean  [128:256)
        prow[64 + d4] = s;      // sum   [256:384)
    }
}

// Kernel 2: MLP over pooled features, GPB graphs per block so W1/W2 L2
// traffic is amortized 16x. 256 threads: tid&127 = output dim, tid>>7
// selects which 8-graph half the thread accumulates.
__global__ __launch_bounds__(256) void mlp_kernel(
    const float* __restrict__ pooled,
    const float* __restrict__ W1, const float* __restrict__ b1,
    const float* __restrict__ W2, const float* __restrict__ b2,
    float* __restrict__ out, int G)
{
    __shared__ float h[GPB][3 * DEPTH];   // 24 KB
    __shared__ float a[GPB][DEPTH];       // 8 KB
    const int tid = threadIdx.x;
    const int g0  = blockIdx.x * GPB;

    // cooperative load of h (pooled rows are contiguous)
    {
        const f4* p4 = reinterpret_cast<const f4*>(pooled + (size_t)g0 * 3 * DEPTH);
        f4* h4 = reinterpret_cast<f4*>(&h[0][0]);
        const int total = GPB * 3 * DEPTH / 4;   // 1536
        for (int i = tid; i < total; i += 256) h4[i] = p4[i];
    }
    __syncthreads();

    const int j  = tid & 127;               // output dim
    const int gh = (tid >> 7) * (GPB / 2);  // 0 or 8

    float acc[GPB / 2];
    #pragma unroll
    for (int i = 0; i < GPB / 2; ++i) acc[i] = b1[j];
    {
        const f4* w1r = reinterpret_cast<const f4*>(W1 + (size_t)j * 3 * DEPTH);
        for (int k = 0; k < 3 * DEPTH / 4; ++k) {
            f4 w = w1r[k];
            #pragma unroll
            for (int i = 0; i < GPB / 2; ++i) {
                f4 hv = reinterpret_cast<const f4*>(h[gh + i])[k];  // LDS broadcast
                acc[i] += w.x * hv.x + w.y * hv.y + w.z * hv.z + w.w * hv.w;
            }
        }
    }
    #pragma unroll
    for (int i = 0; i < GPB / 2; ++i)
        a[gh + i][j] = (acc[i] > 0.f) ? acc[i] : 0.01f * acc[i];
    __syncthreads();

    #pragma unroll
    for (int i = 0; i < GPB / 2; ++i) acc[i] = b2[j];
    {
        const f4* w2r = reinterpret_cast<const f4*>(W2 + (size_t)j * DEPTH);
        for (int k = 0; k < DEPTH / 4; ++k) {
            f4 w = w2r[k];
            #pragma unroll
            for (int i = 0; i < GPB / 2; ++i) {
                f4 av = reinterpret_cast<const f4*>(a[gh + i])[k];  // LDS broadcast
                acc[i] += w.x * av.x + w.y * av.y + w.z * av.z + w.w * av.w;
            }
        }
    }
    #pragma unroll
    for (int i = 0; i < GPB / 2; ++i) {
        const int g = g0 + gh + i;
        if (g < G) out[(size_t)g * DEPTH + j] = acc[i];
    }
}

extern "C" void kernel_launch(void* const* d_in, const int* in_sizes, int n_in,
                              void* d_out, int out_size, void* d_ws, size_t ws_size,
                              hipStream_t stream) {
    const float* x     = (const float*)d_in[0];
    const int*   batch = (const int*)d_in[1];
    const float* W1 = (const float*)d_in[3];
    const float* b1 = (const float*)d_in[4];
    const float* W2 = (const float*)d_in[5];
    const float* b2 = (const float*)d_in[6];
    float* out = (float*)d_out;

    const int N = in_sizes[0] / DEPTH;   // 2,000,000 nodes
    const int G = out_size / DEPTH;      // 4096 graphs

    float* pooled = (float*)d_ws;        // G * 384 floats, fully rewritten

    pool_kernel<<<G, 256, 0, stream>>>(
        (const f4*)x, batch, pooled, N, G);
    mlp_kernel<<<(G + GPB - 1) / GPB, 256, 0, stream>>>(
        pooled, W1, b1, W2, b2, out, G);
}